// Round 2
// baseline (3536.188 us; speedup 1.0000x reference)
//
#include <hip/hip_runtime.h>
#include <math.h>

// Problem constants (fixed by the reference setup)
#define NTOK  65536      // B*T = 16*4096
#define DDIM  256
#define KCODE 1024
#define LLAY  8
#define NQ    (NTOK*DDIM)        // 16777216 floats: quantized output
#define LOSS_OFF NQ              // 1 float: total loss
#define IDX_OFF  (NQ+1)          // 524288 floats: indices [B,T,L] as float

// ws layout (floats)
#define ET_FLOATS (LLAY*DDIM*KCODE)   // 2097152  (8 MB): E transposed [l][d][k]
// ekk at ws + ET_FLOATS: [l][k] = ||e||^2  (8192 floats)

// ---------------------------------------------------------------------------
// Kernel 0: transpose embeddings E[l][k][d] -> ET[l][d][k]; zero the loss slot
// ---------------------------------------------------------------------------
__global__ __launch_bounds__(256) void rvq_transpose(const float* __restrict__ E,
                                                     float* __restrict__ ws,
                                                     float* __restrict__ out) {
    __shared__ float tile[32][33];
    int b  = blockIdx.x;          // 2048 blocks = 8 l * 8 dt * 32 kt
    int l  = b >> 8;
    int dt = (b >> 5) & 7;
    int kt = b & 31;
    int d0 = dt * 32, k0 = kt * 32;
    const float* Eb = E  + l * KCODE * DDIM;
    float*       ET = ws + l * DDIM * KCODE;
    int lane = threadIdx.x & 31;
    int row  = threadIdx.x >> 5;  // 0..7
#pragma unroll
    for (int it = 0; it < 4; ++it) {
        int kk = row + it * 8;
        tile[kk][lane] = Eb[(k0 + kk) * DDIM + d0 + lane];   // coalesced in d
    }
    __syncthreads();
#pragma unroll
    for (int it = 0; it < 4; ++it) {
        int dd = row + it * 8;
        ET[(d0 + dd) * KCODE + k0 + lane] = tile[lane][dd];  // coalesced in k
    }
    if (b == 0 && threadIdx.x == 0) out[LOSS_OFF] = 0.0f;
}

// ---------------------------------------------------------------------------
// Kernel 1: per-code ||e||^2: f32 squares, f64 accumulate, narrow to f32.
// (np does f32 pairwise; any value within a few ulps gives identical argmin
//  because a shared-per-k shift of <1 ulp only matters at cell midpoints.)
// ---------------------------------------------------------------------------
__global__ __launch_bounds__(256) void rvq_ekk(const float* __restrict__ E,
                                               float* __restrict__ ws) {
    int gid = blockIdx.x * 256 + threadIdx.x;   // 8192 = L*K
    const float4* rowp = (const float4*)(E + (size_t)gid * DDIM);
    double s = 0.0;
#pragma unroll 8
    for (int i = 0; i < 64; ++i) {
        float4 v = rowp[i];
        float p0 = v.x * v.x;   // f32 square first (matches flat*flat temp)
        float p1 = v.y * v.y;
        float p2 = v.z * v.z;
        float p3 = v.w * v.w;
        s += (double)p0; s += (double)p1; s += (double)p2; s += (double)p3;
    }
    ws[ET_FLOATS + gid] = (float)s;
}

// ---------------------------------------------------------------------------
// Main kernel: 64 tokens per block, loops all 8 layers internally.
// Emulates the np f32 reference bitwise where it matters:
//   M_nk = sequential ascending-d f32 fma chain  (BLAS sgemm microkernel order)
//   dist = fl32( fl32(A_n + B_k) - 2*M_nk )
//   argmin with lowest-index tie-break (np.argmin)
//   residual: d1=fl(q-r); qst=fl(r+d1); rn=fl(r-qst)   (straight-through)
// ---------------------------------------------------------------------------
__global__ __launch_bounds__(256, 2) void rvq_main(const float* __restrict__ x,
                                                   const float* __restrict__ E,
                                                   const float* __restrict__ ws,
                                                   float* __restrict__ out) {
    // LDS (floats): Rt[256][68] | Ets 2048 (alias: Ad 256 dbl, scr2 256 f2) |
    //               Af[64] | kw[64] | lred[4]
    __shared__ __align__(16) float smem[19588];
    float*   Rt   = smem;                       // residual^T [d][token], stride 68
    float*   Ets  = smem + 17408;               // staged E^T chunk [8][256]
    double*  Ad   = (double*)(smem + 17408);    // alias: A partial sums (256 dbl)
    float2*  scr2 = (float2*)(smem + 17408);    // alias: argmin merge scratch
    float*   Af   = smem + 19456;               // per-token ||r||^2 (f32)
    int*     kw   = (int*)(smem + 19520);       // winning code per token
    float*   lred = smem + 19584;               // per-wave loss partials

    const int tid = threadIdx.x;
    const int ty  = tid & 7;     // token group: tokens ty*8 .. ty*8+7
    const int tx  = tid >> 3;    // code group within k-tile
    const int m0  = blockIdx.x * 64;
    const float* ekk = ws + ET_FLOATS;

    // ---- load residual = x, transposed into LDS ----
#pragma unroll
    for (int u = 0; u < 16; ++u) {
        int id4 = u * 256 + tid;          // 4096 float4
        int mm  = id4 >> 6;
        int d4  = (id4 & 63) << 2;
        float4 v = *(const float4*)(x + (size_t)(m0 + mm) * DDIM + d4);
        Rt[(d4 + 0) * 68 + mm] = v.x;
        Rt[(d4 + 1) * 68 + mm] = v.y;
        Rt[(d4 + 2) * 68 + mm] = v.z;
        Rt[(d4 + 3) * 68 + mm] = v.w;
    }

    float lacc = 0.f;

    for (int l = 0; l < LLAY; ++l) {
        const float* ETl = ws + (size_t)l * DDIM * KCODE;
        const float* El  = E  + (size_t)l * KCODE * DDIM;

        // ---- A_m = sum_d fl32(r^2), f64-accurate, narrowed to f32 ----
        __syncthreads();   // Rt stable; Ad region free
        {
            int m = tid >> 2, c = tid & 3;
            double sa = 0.0;
#pragma unroll 8
            for (int j = 0; j < 64; ++j) {
                float r = Rt[(c * 64 + j) * 68 + m];
                float p = r * r;           // f32 square first
                sa += (double)p;
            }
            Ad[tid] = sa;                  // Ad[m*4+c]
        }
        __syncthreads();
        if (tid < 64) {
            double a = Ad[tid * 4] + Ad[tid * 4 + 1] + Ad[tid * 4 + 2] + Ad[tid * 4 + 3];
            Af[tid] = (float)a;
        }
        __syncthreads();

        float Ai[8];
#pragma unroll
        for (int i = 0; i < 8; ++i) Ai[i] = Af[ty * 8 + i];

        float s1[8];
        int   k1[8];
#pragma unroll
        for (int i = 0; i < 8; ++i) { s1[i] = INFINITY; k1[i] = 0x7fffffff; }

        // ---- score all 1024 codes in 4 k-tiles of 256 ----
        for (int kt = 0; kt < 4; ++kt) {
            float acc[8][8];
#pragma unroll
            for (int i = 0; i < 8; ++i)
#pragma unroll
                for (int j = 0; j < 8; ++j) acc[i][j] = 0.f;

            for (int dc = 0; dc < 32; ++dc) {
                __syncthreads();
                // stage E^T chunk [8 d][256 k]
#pragma unroll
                for (int u = 0; u < 2; ++u) {
                    int id4 = u * 256 + tid;
                    int dd  = id4 >> 6;
                    int kk4 = (id4 & 63) << 2;
                    *(float4*)(Ets + dd * 256 + kk4) =
                        *(const float4*)(ETl + (size_t)(dc * 8 + dd) * KCODE + kt * 256 + kk4);
                }
                __syncthreads();
#pragma unroll
                for (int dd = 0; dd < 8; ++dd) {
                    int d = dc * 8 + dd;
                    float4 ra = *(float4*)(Rt + d * 68 + ty * 8);
                    float4 rb = *(float4*)(Rt + d * 68 + ty * 8 + 4);
                    float4 ea = *(float4*)(Ets + dd * 256 + tx * 8);
                    float4 eb = *(float4*)(Ets + dd * 256 + tx * 8 + 4);
                    float rr[8] = {ra.x, ra.y, ra.z, ra.w, rb.x, rb.y, rb.z, rb.w};
                    float ee[8] = {ea.x, ea.y, ea.z, ea.w, eb.x, eb.y, eb.z, eb.w};
                    // ascending-d single fma chain per (i,j): bitwise == sgemm
#pragma unroll
                    for (int i = 0; i < 8; ++i)
#pragma unroll
                        for (int j = 0; j < 8; ++j)
                            acc[i][j] = fmaf(rr[i], ee[j], acc[i][j]);
                }
            }

            // dists for this k-tile: fl32(fl32(A+B) - 2*M); argmin w/ low-index ties
            float4 ka = *(const float4*)(ekk + l * KCODE + kt * 256 + tx * 8);
            float4 kb = *(const float4*)(ekk + l * KCODE + kt * 256 + tx * 8 + 4);
            float ek[8] = {ka.x, ka.y, ka.z, ka.w, kb.x, kb.y, kb.z, kb.w};
#pragma unroll
            for (int i = 0; i < 8; ++i)
#pragma unroll
                for (int j = 0; j < 8; ++j) {
                    float u = Ai[i] + ek[j];          // fl32(A + B)
                    float s = u - 2.0f * acc[i][j];   // fl32(u - 2M) (2M exact)
                    int   k = kt * 256 + tx * 8 + j;
                    if ((s < s1[i]) || (s == s1[i] && k < k1[i])) { s1[i] = s; k1[i] = k; }
                }
        }

        // ---- argmin merge across tx within the wave (tx bits = tid[3:5]) ----
#pragma unroll
        for (int off = 8; off <= 32; off <<= 1) {
#pragma unroll
            for (int i = 0; i < 8; ++i) {
                float ps = __shfl_xor(s1[i], off, 64);
                int   pk = __shfl_xor(k1[i], off, 64);
                if ((ps < s1[i]) || (ps == s1[i] && pk < k1[i])) { s1[i] = ps; k1[i] = pk; }
            }
        }

        __syncthreads();   // Ets reads done before aliased scr2 writes
        if ((tid & 56) == 0) {
            int w = tid >> 6;
#pragma unroll
            for (int i = 0; i < 8; ++i)
                scr2[w * 64 + ty * 8 + i] = make_float2(s1[i], __int_as_float(k1[i]));
        }
        __syncthreads();

        // ---- merge across the 4 waves; write index output ----
        if (tid < 64) {
            float2 a = scr2[tid];
            float fs = a.x; int fk = __float_as_int(a.y);
#pragma unroll
            for (int w = 1; w < 4; ++w) {
                float2 bb = scr2[w * 64 + tid];
                float ps = bb.x; int pk = __float_as_int(bb.y);
                if ((ps < fs) || (ps == fs && pk < fk)) { fs = ps; fk = pk; }
            }
            kw[tid] = fk;
            out[IDX_OFF + (size_t)(m0 + tid) * LLAY + l] = (float)fk;
        }
        __syncthreads();

        // ---- residual update (exact straight-through f32 ops) + loss ----
        {
            int m  = tid >> 2;
            int ds = (tid & 3) * 64;
            int kwm = kw[m];
            const float* erow = El + (size_t)kwm * DDIM;
            const float* xrow = x  + (size_t)(m0 + m) * DDIM;
            float*       orow = out + (size_t)(m0 + m) * DDIM;
#pragma unroll 4
            for (int q = 0; q < 16; ++q) {
                int d = ds + q * 4;
                float4 e4 = *(const float4*)(erow + d);
                float qv[4] = {e4.x, e4.y, e4.z, e4.w};
                float rn[4];
#pragma unroll
                for (int t = 0; t < 4; ++t) {
                    float r   = Rt[(d + t) * 68 + m];
                    float d1  = qv[t] - r;     // fl(q - r)  == diff (loss term)
                    float qst = r + d1;        // fl(r + d1) == q_st
                    rn[t]     = r - qst;       // fl(r - q_st) == new residual
                    Rt[(d + t) * 68 + m] = rn[t];
                    lacc = fmaf(d1, d1, lacc);
                }
                if (l == LLAY - 1) {
                    float4 x4 = *(const float4*)(xrow + d);
                    *(float4*)(orow + d) =
                        make_float4(x4.x - rn[0], x4.y - rn[1], x4.z - rn[2], x4.w - rn[3]);
                }
            }
        }
        __syncthreads();
    }

    // ---- loss reduction: wave -> block -> global atomic ----
#pragma unroll
    for (int off = 32; off > 0; off >>= 1) lacc += __shfl_down(lacc, off, 64);
    if ((tid & 63) == 0) lred[tid >> 6] = lacc;
    __syncthreads();
    if (tid == 0) {
        float t = lred[0] + lred[1] + lred[2] + lred[3];
        atomicAdd(out + LOSS_OFF, t * (0.25f / 16777216.0f));
    }
}

// ---------------------------------------------------------------------------
extern "C" void kernel_launch(void* const* d_in, const int* in_sizes, int n_in,
                              void* d_out, int out_size, void* d_ws, size_t ws_size,
                              hipStream_t stream) {
    const float* x  = (const float*)d_in[0];
    const float* E  = (const float*)d_in[1];
    float* out = (float*)d_out;
    float* ws  = (float*)d_ws;   // needs (2097152 + 8192) * 4 B = ~8.03 MB

    rvq_transpose<<<dim3(2048), dim3(256), 0, stream>>>(E, ws, out);
    rvq_ekk<<<dim3(32), dim3(256), 0, stream>>>(E, ws);
    rvq_main<<<dim3(1024), dim3(256), 0, stream>>>(x, E, ws, out);
}

// Round 3
// 2752.318 us; speedup vs baseline: 1.2848x; 1.2848x over previous
//
#include <hip/hip_runtime.h>
#include <math.h>

// Problem constants (fixed by the reference setup)
#define NTOK  65536      // B*T = 16*4096
#define DDIM  256
#define KCODE 1024
#define LLAY  8
#define NQ    (NTOK*DDIM)        // 16777216 floats: quantized output
#define LOSS_OFF NQ              // 1 float: total loss
#define IDX_OFF  (NQ+1)          // 524288 floats: indices [B,T,L] as float

// ws layout (bytes):
//   [0, 4MB)     E_hi  bf16 [l][k][d]
//   [4MB, 8MB)   E_lo  bf16 [l][k][d]
//   [8MB, +32KB) ekk   f32  [l][k]  = ||e||^2 (f64-accumulated, narrowed)
#define EHI_OFF 0
#define ELO_OFF (LLAY*KCODE*DDIM)          // in ushort elements: 2097152
#define EKK_BYTE_OFF 8388608

typedef __attribute__((ext_vector_type(8))) short short8;   // 8 bf16 (4 VGPR)
typedef __attribute__((ext_vector_type(4))) float f32x4;    // MFMA C/D frag

__device__ __forceinline__ unsigned short f2bf(float f) {   // RTNE f32->bf16
    unsigned u = __float_as_uint(f);
    u = u + 0x7fffu + ((u >> 16) & 1u);
    return (unsigned short)(u >> 16);
}
__device__ __forceinline__ float bf2f(unsigned short h) {
    return __uint_as_float(((unsigned)h) << 16);
}

// ---------------------------------------------------------------------------
// Prep kernel A: split E f32 -> bf16 hi/lo pair in ws; zero the loss slot.
// ---------------------------------------------------------------------------
__global__ __launch_bounds__(256) void rvq_prep(const float* __restrict__ E,
                                                unsigned short* __restrict__ Ehi,
                                                unsigned short* __restrict__ Elo,
                                                float* __restrict__ out) {
    size_t g4 = (size_t)blockIdx.x * 256 + threadIdx.x;   // 524288 float4 groups
    const float4 v = *(const float4*)(E + g4 * 4);
    unsigned short h[4], lo[4];
    float f[4] = {v.x, v.y, v.z, v.w};
#pragma unroll
    for (int i = 0; i < 4; ++i) {
        h[i]  = f2bf(f[i]);
        lo[i] = f2bf(f[i] - bf2f(h[i]));
    }
    *(ushort4*)(Ehi + g4 * 4) = make_ushort4(h[0], h[1], h[2], h[3]);
    *(ushort4*)(Elo + g4 * 4) = make_ushort4(lo[0], lo[1], lo[2], lo[3]);
    if (blockIdx.x == 0 && threadIdx.x == 0) out[LOSS_OFF] = 0.0f;
}

// ---------------------------------------------------------------------------
// Prep kernel B: per-code ||e||^2 (f32 squares, f64 accumulate, narrow).
// Validated bitwise-compatible with the np reference in round 2.
// ---------------------------------------------------------------------------
__global__ __launch_bounds__(256) void rvq_ekk(const float* __restrict__ E,
                                               float* __restrict__ ekk) {
    int gid = blockIdx.x * 256 + threadIdx.x;   // 8192 = L*K
    const float4* rowp = (const float4*)(E + (size_t)gid * DDIM);
    double s = 0.0;
#pragma unroll 8
    for (int i = 0; i < 64; ++i) {
        float4 v = rowp[i];
        float p0 = v.x * v.x, p1 = v.y * v.y, p2 = v.z * v.z, p3 = v.w * v.w;
        s += (double)p0; s += (double)p1; s += (double)p2; s += (double)p3;
    }
    ekk[gid] = (float)s;
}

// ---------------------------------------------------------------------------
// top-2 merge with (score, index) lexicographic order (np.argmin ties)
// ---------------------------------------------------------------------------
__device__ __forceinline__ void merge2(float& s1, int& k1, float& s2, int& k2,
                                       float ps1, int pk1, float ps2, int pk2) {
    bool pb = (ps1 < s1) || (ps1 == s1 && pk1 < k1);
    if (pb) {
        bool mb = (s1 < ps2) || (s1 == ps2 && k1 < pk2);
        float ns2 = mb ? s1 : ps2; int nk2 = mb ? k1 : pk2;
        s1 = ps1; k1 = pk1; s2 = ns2; k2 = nk2;
    } else {
        bool mb = (ps1 < s2) || (ps1 == s2 && pk1 < k2);
        if (mb) { s2 = ps1; k2 = pk1; }
    }
}

// ---------------------------------------------------------------------------
// Main kernel: 64 tokens/block, 4 waves.
//   wave w: token-half th=w&1 (32 tokens, 2 MFMA tiles), code-half ch=w>>1 (512)
//   approx scores via bf16x3 MFMA (hh+hl+lh) -> per-lane top-2 -> lane merge ->
//   4 candidates/token -> exact f32-chain rescore (bitwise np semantics) ->
//   winner -> residual update in LDS (exact straight-through f32 ops).
// ---------------------------------------------------------------------------
__global__ __launch_bounds__(256, 2) void rvq_main(const float* __restrict__ x,
                                                   const float* __restrict__ E,
                                                   const unsigned short* __restrict__ Ehi,
                                                   const unsigned short* __restrict__ Elo,
                                                   const float* __restrict__ ekk,
                                                   float* __restrict__ out) {
    __shared__ __align__(16) float  Rt[64 * 260];   // residual f32 [tok][260pad]
    __shared__ double Ad[256];                      // A_n partial sums
    __shared__ float4 cand[128];                    // [tok][ch]: s1,k1,s2,k2
    __shared__ float  Af[64];                       // per-token ||r||^2 (f32)
    __shared__ int    kw[64];                       // winning code per token
    __shared__ float  lred[4];                      // per-wave loss partials

    const int tid  = threadIdx.x;
    const int lane = tid & 63;
    const int wv   = tid >> 6;
    const int th   = wv & 1;       // token half
    const int ch   = wv >> 1;      // code half
    const int col  = lane & 15;    // MFMA n / m index within tile
    const int quad = lane >> 4;    // MFMA k-chunk selector
    const int m0   = blockIdx.x * 64;

    // ---- load residual = x into LDS (row-major, pad 260) ----
#pragma unroll
    for (int u = 0; u < 16; ++u) {
        int id4 = u * 256 + tid;          // 4096 float4
        int mm  = id4 >> 6;
        int d4  = (id4 & 63) << 2;
        float4 v = *(const float4*)(x + (size_t)(m0 + mm) * DDIM + d4);
        *(float4*)(&Rt[mm * 260 + d4]) = v;
    }

    float lacc = 0.f;

    for (int l = 0; l < LLAY; ++l) {
        const float* El = E + (size_t)l * KCODE * DDIM;
        __syncthreads();   // Rt stable (prev layer update done)

        // ---- A_m = sum_d fl32(r^2), f64-accurate, narrowed to f32 ----
        {
            int m = tid >> 2, c = tid & 3;
            const float* rr = &Rt[m * 260 + c * 64];
            double sa = 0.0;
#pragma unroll 4
            for (int q = 0; q < 16; ++q) {
                float4 v = *(const float4*)(rr + q * 4);
                float p0 = v.x * v.x, p1 = v.y * v.y, p2 = v.z * v.z, p3 = v.w * v.w;
                sa += (double)p0; sa += (double)p1; sa += (double)p2; sa += (double)p3;
            }
            Ad[tid] = sa;
        }
        __syncthreads();
        if (tid < 64) {
            double a = Ad[tid * 4] + Ad[tid * 4 + 1] + Ad[tid * 4 + 2] + Ad[tid * 4 + 3];
            Af[tid] = (float)a;
        }
        __syncthreads();

        // ---- per-lane A values for the 8 (tile,reg) accumulator rows ----
        float Ai[2][4];
#pragma unroll
        for (int tt = 0; tt < 2; ++tt)
#pragma unroll
            for (int g = 0; g < 4; ++g)
                Ai[tt][g] = Af[th * 32 + tt * 16 + quad * 4 + g];

        // ---- build A-frag cache (bf16 hi/lo) for full K from Rt ----
        short8 ah[2][8], al[2][8];
#pragma unroll
        for (int tt = 0; tt < 2; ++tt) {
            const float* rrow = &Rt[(th * 32 + tt * 16 + col) * 260];
#pragma unroll
            for (int ks = 0; ks < 8; ++ks) {
                float4 p = *(const float4*)(rrow + ks * 32 + quad * 8);
                float4 q = *(const float4*)(rrow + ks * 32 + quad * 8 + 4);
                float f[8] = {p.x, p.y, p.z, p.w, q.x, q.y, q.z, q.w};
#pragma unroll
                for (int j = 0; j < 8; ++j) {
                    unsigned short h = f2bf(f[j]);
                    ah[tt][ks][j] = (short)h;
                    al[tt][ks][j] = (short)f2bf(f[j] - bf2f(h));
                }
            }
        }

        // ---- approx scoring: 32 code-tiles of 16, top-2 per lane-stream ----
        float ts1[2][4], ts2[2][4];
        int   tc1[2][4], tc2[2][4];
#pragma unroll
        for (int tt = 0; tt < 2; ++tt)
#pragma unroll
            for (int g = 0; g < 4; ++g) {
                ts1[tt][g] = INFINITY; ts2[tt][g] = INFINITY;
                tc1[tt][g] = 0x7fff;   tc2[tt][g] = 0x7fff;
            }

        const int co = ch * 512;
        const size_t lbase = (size_t)l * KCODE * DDIM;
        for (int c = 0; c < 32; ++c) {
            const int code = co + c * 16 + col;
            const unsigned short* bh_p = Ehi + lbase + (size_t)code * DDIM + quad * 8;
            const unsigned short* bl_p = Elo + lbase + (size_t)code * DDIM + quad * 8;
            float ekv = ekk[l * KCODE + code];

            short8 bh[8], bl[8];
#pragma unroll
            for (int ks = 0; ks < 8; ++ks) bh[ks] = *(const short8*)(bh_p + ks * 32);
#pragma unroll
            for (int ks = 0; ks < 8; ++ks) bl[ks] = *(const short8*)(bl_p + ks * 32);

            f32x4 acc0 = {0.f, 0.f, 0.f, 0.f};
            f32x4 acc1 = {0.f, 0.f, 0.f, 0.f};
#pragma unroll
            for (int ks = 0; ks < 8; ++ks) {
                acc0 = __builtin_amdgcn_mfma_f32_16x16x32_bf16(ah[0][ks], bh[ks], acc0, 0, 0, 0);
                acc1 = __builtin_amdgcn_mfma_f32_16x16x32_bf16(ah[1][ks], bh[ks], acc1, 0, 0, 0);
                acc0 = __builtin_amdgcn_mfma_f32_16x16x32_bf16(ah[0][ks], bl[ks], acc0, 0, 0, 0);
                acc1 = __builtin_amdgcn_mfma_f32_16x16x32_bf16(ah[1][ks], bl[ks], acc1, 0, 0, 0);
                acc0 = __builtin_amdgcn_mfma_f32_16x16x32_bf16(al[0][ks], bh[ks], acc0, 0, 0, 0);
                acc1 = __builtin_amdgcn_mfma_f32_16x16x32_bf16(al[1][ks], bh[ks], acc1, 0, 0, 0);
            }

#pragma unroll
            for (int tt = 0; tt < 2; ++tt)
#pragma unroll
                for (int g = 0; g < 4; ++g) {
                    float v = tt ? acc1[g] : acc0[g];
                    float s = fmaf(-2.f, v, Ai[tt][g] + ekv);
                    if (s < ts1[tt][g]) {
                        ts2[tt][g] = ts1[tt][g]; tc2[tt][g] = tc1[tt][g];
                        ts1[tt][g] = s;          tc1[tt][g] = c;
                    } else if (s < ts2[tt][g]) {
                        ts2[tt][g] = s; tc2[tt][g] = c;
                    }
                }
        }

        // ---- convert tile-codes to global code indices ----
        int ik1[2][4], ik2[2][4];
#pragma unroll
        for (int tt = 0; tt < 2; ++tt)
#pragma unroll
            for (int g = 0; g < 4; ++g) {
                ik1[tt][g] = co + (tc1[tt][g] << 4) + col;
                ik2[tt][g] = co + (tc2[tt][g] << 4) + col;
            }

        // ---- merge top-2 across the 16 cols (lanes differing in bits 0..3) ----
#pragma unroll
        for (int off = 1; off <= 8; off <<= 1) {
#pragma unroll
            for (int tt = 0; tt < 2; ++tt)
#pragma unroll
                for (int g = 0; g < 4; ++g) {
                    float os1 = __shfl_xor(ts1[tt][g], off, 64);
                    int   ok1 = __shfl_xor(ik1[tt][g], off, 64);
                    float os2 = __shfl_xor(ts2[tt][g], off, 64);
                    int   ok2 = __shfl_xor(ik2[tt][g], off, 64);
                    merge2(ts1[tt][g], ik1[tt][g], ts2[tt][g], ik2[tt][g],
                           os1, ok1, os2, ok2);
                }
        }
        if (col == 0) {
#pragma unroll
            for (int tt = 0; tt < 2; ++tt)
#pragma unroll
                for (int g = 0; g < 4; ++g) {
                    int tokl = th * 32 + tt * 16 + quad * 4 + g;
                    cand[tokl * 2 + ch] = make_float4(ts1[tt][g], __int_as_float(ik1[tt][g]),
                                                      ts2[tt][g], __int_as_float(ik2[tt][g]));
                }
        }
        __syncthreads();

        // ---- exact f32 rescore of the 4 candidates (bitwise np semantics) ----
        {
            int m = tid >> 2, j = tid & 3;
            float4 cd = cand[m * 2 + (j >> 1)];
            int myk = (j & 1) ? __float_as_int(cd.w) : __float_as_int(cd.y);
            const float* erow = El + (size_t)myk * DDIM;
            const float* rrow = &Rt[m * 260];
            float M = 0.f;
#pragma unroll 8
            for (int q = 0; q < 64; ++q) {     // ascending-d single fma chain
                float4 e4 = *(const float4*)(erow + q * 4);
                float4 r4 = *(const float4*)(rrow + q * 4);
                M = fmaf(r4.x, e4.x, M);
                M = fmaf(r4.y, e4.y, M);
                M = fmaf(r4.z, e4.z, M);
                M = fmaf(r4.w, e4.w, M);
            }
            float u = Af[m] + ekk[l * KCODE + myk];   // fl32(A + B)
            float s = fmaf(-2.f, M, u);               // fl32(u - 2M)
#pragma unroll
            for (int off = 1; off <= 2; off <<= 1) {
                float os = __shfl_xor(s, off, 64);
                int   ok = __shfl_xor(myk, off, 64);
                if ((os < s) || (os == s && ok < myk)) { s = os; myk = ok; }
            }
            if (j == 0) {
                kw[m] = myk;
                out[IDX_OFF + (size_t)(m0 + m) * LLAY + l] = (float)myk;
            }
        }
        __syncthreads();

        // ---- residual update (exact straight-through f32 ops) + loss ----
        {
            int m  = tid >> 2;
            int ds = (tid & 3) * 64;
            int kwm = kw[m];
            const float* erow = El + (size_t)kwm * DDIM;
            const float* xrow = x  + (size_t)(m0 + m) * DDIM;
            float*       orow = out + (size_t)(m0 + m) * DDIM;
            float*       rrow = &Rt[m * 260];
#pragma unroll 4
            for (int q = 0; q < 16; ++q) {
                int d = ds + q * 4;
                float4 e4 = *(const float4*)(erow + d);
                float4 r4 = *(const float4*)(rrow + d);
                float qv[4] = {e4.x, e4.y, e4.z, e4.w};
                float rv[4] = {r4.x, r4.y, r4.z, r4.w};
                float rn[4];
#pragma unroll
                for (int t = 0; t < 4; ++t) {
                    float d1  = qv[t] - rv[t];   // fl(q - r)  (loss term)
                    float qst = rv[t] + d1;      // fl(r + d1) (straight-through)
                    rn[t]     = rv[t] - qst;     // fl(r - q_st)
                    lacc = fmaf(d1, d1, lacc);
                }
                *(float4*)(rrow + d) = make_float4(rn[0], rn[1], rn[2], rn[3]);
                if (l == LLAY - 1) {
                    float4 x4 = *(const float4*)(xrow + d);
                    *(float4*)(orow + d) =
                        make_float4(x4.x - rn[0], x4.y - rn[1], x4.z - rn[2], x4.w - rn[3]);
                }
            }
        }
    }

    // ---- loss reduction: wave -> block -> global atomic ----
#pragma unroll
    for (int off = 32; off > 0; off >>= 1) lacc += __shfl_down(lacc, off, 64);
    __syncthreads();
    if ((tid & 63) == 0) lred[tid >> 6] = lacc;
    __syncthreads();
    if (tid == 0) {
        float t = lred[0] + lred[1] + lred[2] + lred[3];
        atomicAdd(out + LOSS_OFF, t * (0.25f / 16777216.0f));
    }
}

// ---------------------------------------------------------------------------
extern "C" void kernel_launch(void* const* d_in, const int* in_sizes, int n_in,
                              void* d_out, int out_size, void* d_ws, size_t ws_size,
                              hipStream_t stream) {
    const float* x  = (const float*)d_in[0];
    const float* E  = (const float*)d_in[1];
    float* out = (float*)d_out;
    unsigned short* Ehi = (unsigned short*)d_ws;
    unsigned short* Elo = Ehi + ELO_OFF;
    float* ekkp = (float*)((char*)d_ws + EKK_BYTE_OFF);   // needs ~8.42 MB ws

    rvq_prep<<<dim3(2048), dim3(256), 0, stream>>>(E, Ehi, Elo, out);
    rvq_ekk<<<dim3(32), dim3(256), 0, stream>>>(E, ekkp);
    rvq_main<<<dim3(1024), dim3(256), 0, stream>>>(x, E, Ehi, Elo, ekkp, out);
}